// Round 8
// baseline (142.702 us; speedup 1.0000x reference)
//
#include <hip/hip_runtime.h>

// Depthwise Gaussian blur K=121, replicate pad, separable, fp32. FUSED.
// R15 = R14 resubmitted verbatim (R14's bench failed on infra: "MI355X
// container failed twice"; code re-audited -- V-window algebra, buffer
// rotation, grid map, halo, store pattern all check out).
// R14 = R13 with TILE HEIGHT 8 -> 16 (same 256 thr x 2 cols, same store
// pattern per instruction). V window = 136 rows / 16 output rows:
// loads per output 8.5 -> 4.5, L2-read bytes halved (V was doubly
// saturated: VALU 13.7us =~ L2 12.4us per CU). V uses a 3-buffer row
// rotation (24-row register window); taps 121..127 are zero so the
// 8-row overrun at the last octet is harmless. H phase = R13's verbatim,
// run twice (rows r, r+8) with register reuse. LDS 43KB -> 3 blocks/CU
// = 12 waves/CU = today's MEASURED resident occupancy, so effective
// parallelism is unchanged.
// R13 learnings kept: scalar weights from d_ws (pre-normalized), clean
// global-side geometry (FETCH 12MB / WRITE 24.6MB = output), XOR-swizzle
// LDS. Conflict counter ~8.6M is inherent 64-lane/32-bank aliasing
// (constant across R6/R7/R13 swizzle variants) -- not worth chasing;
// LDS BW is only ~6us/CU.

#define HH    512
#define WW    512
#define PLANE (512 * 512)
#define NIMG  24
#define TH    16                     // tile height (output rows per block)
#define ROWF  672                    // 168 16B-units/row, swizzle-bijective

// ---- pre-kernel: 128 normalized 1-D taps -> d_ws --------------------------
__global__ void wk_prep(const float* __restrict__ sigma,
                        float* __restrict__ wg) {
    const int tid = threadIdx.x;                     // 128 threads, 1 block
    const float s = sigma[0] * 8.0f + 16.0f;
    const float inv2v = 1.0f / (2.0f * s * s);
    float sum = 0.0f;
    #pragma unroll
    for (int k = 0; k <= 120; ++k) {
        const float c = (float)k - 60.0f;
        sum += __expf(-c * c * inv2v);
    }
    float g = 0.0f;
    if (tid < 121) {
        const float c = (float)tid - 60.0f;
        g = __expf(-c * c * inv2v);
    }
    wg[tid] = g / sum;               // taps 121..127 exactly 0
}

// dword offset within an LDS row for padded column `col` (swizzled)
__device__ __forceinline__ int swz_off(int col) {
    const int u = col >> 2;
    return ((u ^ ((u >> 3) & 7)) << 2) + (col & 3);
}

// Vertical octet, 16 output rows, 24-row register window (C0,C1,NXT).
// At octet KO: C0 = rows r0-60+8KO.., C1 = +8, NXT <- rows r0-44+8KO..
// vac[j] += w[8KO+ki] * row[r0-60+8KO+ki+j], j=0..15, idx=ki+j in 0..22.
#define V_OCT3(C0, C1, NXT, KO)                                           \
    { *(float4*)&wq[0] = *(const float4*)&wg[(KO) * 8];                   \
      *(float4*)&wq[4] = *(const float4*)&wg[(KO) * 8 + 4];               \
      _Pragma("unroll")                                                   \
      for (int ki = 0; ki < 8; ++ki) {                                    \
          int rr = r0 - 44 + (KO) * 8 + ki;                               \
          rr = rr < 0 ? 0 : (rr > HH - 1 ? HH - 1 : rr);                  \
          NXT[ki] = *(const float2*)&src[(size_t)rr * WW];                \
          const float wk = wq[ki];                                        \
          _Pragma("unroll")                                               \
          for (int j = 0; j < 16; ++j) {                                  \
              const int idx = ki + j;                                     \
              const float2 v = (idx < 8) ? C0[idx]                        \
                             : (idx < 16) ? C1[idx - 8] : NXT[idx - 16];  \
              vac[j].x += wk * v.x; vac[j].y += wk * v.y;                 \
          }                                                               \
      }                                                                   \
    }

// Load group G (span A) and G+32 (span B): one swizzled address serves all
// four b128s -- phys(2G+1)=phys(2G)^1, phys(u+64)=phys(u)+64 (+256 floats).
#define LOADG2(DA, DB, G)                                                 \
    { const int u_  = 2 * (G);                                            \
      const int o1_ = (u_ ^ ((u_ >> 3) & 7)) << 2;                        \
      const int o2_ = o1_ ^ 4;                                            \
      *(float4*)&DA[0] = *(const float4*)(bs + o1_);                      \
      *(float4*)&DA[4] = *(const float4*)(bs + o2_);                      \
      *(float4*)&DB[0] = *(const float4*)(bs + o1_ + 256);                \
      *(float4*)&DB[4] = *(const float4*)(bs + o2_ + 256); }

// One octet, TWO 8-col spans (A: groups L+.., B: groups L+32+..)
#define H_OCT2(A0, A1, A2, A3, B0, B1, B2, B3, KO)                        \
    { LOADG2(A3, B3, L + (KO) + 3)                                        \
      *(float4*)&wq[0] = *(const float4*)&wg[(KO) * 8];                   \
      *(float4*)&wq[4] = *(const float4*)&wg[(KO) * 8 + 4];               \
      _Pragma("unroll")                                                   \
      for (int ki = 0; ki < 8; ++ki) {                                    \
          const float wk = wq[ki];                                        \
          _Pragma("unroll")                                               \
          for (int j = 0; j < 8; ++j) {                                   \
              const int idx = ki + j;                                     \
              const float vA = (idx < 8) ? A0[idx]                        \
                             : (idx < 16) ? A1[idx - 8] : A2[idx - 16];   \
              const float vB = (idx < 8) ? B0[idx]                        \
                             : (idx < 16) ? B1[idx - 8] : B2[idx - 16];   \
              accA[j] += wk * vA;                                         \
              accB[j] += wk * vB;                                         \
          }                                                               \
      }                                                                   \
    }

__global__ __launch_bounds__(256, 3) void blur_fused(
        const float* __restrict__ x, const float* __restrict__ wg,
        float* __restrict__ out) {
    __shared__ float sm[TH * ROWF];                  // 43008 B
    const int tid = threadIdx.x;

    // XCD swizzle: linear id -> contiguous 96-tile span per XCD (%8 rr).
    const int lid   = blockIdx.x + gridDim.x * blockIdx.y;   // 0..767
    const int tile  = (lid & 7) * 96 + (lid >> 3);
    const int r0    = (tile & 31) * TH;              // output rows r0..r0+15
    const int plane = tile >> 5;

    const int c0 = tid * 2;                          // this thread's 2 cols
    const float* __restrict__ src = x + (size_t)plane * PLANE + c0;

    // ---- vertical: 16 rows x 2 cols per thread, 3-buffer row rotation ----
    float2 w0[8], w1[8], w2[8], vac[16];
    float  wq[8];
    #pragma unroll
    for (int m = 0; m < 8; ++m) {                    // rows r0-60..r0-53
        int rr = r0 - 60 + m;
        rr = rr < 0 ? 0 : rr;
        w0[m] = *(const float2*)&src[(size_t)rr * WW];
    }
    #pragma unroll
    for (int m = 0; m < 8; ++m) {                    // rows r0-52..r0-45
        int rr = r0 - 52 + m;
        rr = rr < 0 ? 0 : rr;
        w1[m] = *(const float2*)&src[(size_t)rr * WW];
    }
    #pragma unroll
    for (int j = 0; j < 16; ++j) vac[j] = make_float2(0.f, 0.f);

    #pragma unroll 1
    for (int ko = 0; ko < 15; ko += 3) {             // 15 octets, period-3 rot
        V_OCT3(w0, w1, w2, ko)
        V_OCT3(w1, w2, w0, ko + 1)
        V_OCT3(w2, w0, w1, ko + 2)
    }
    V_OCT3(w0, w1, w2, 15)                           // taps 120..127 (121+ = 0)

    // write intermediate at halo offset +60 (swizzled; float2 stays in-unit)
    {
        const int off = swz_off(c0 + 60);            // col even -> within-unit
        #pragma unroll
        for (int j = 0; j < TH; ++j)
            *(float2*)&sm[j * ROWF + off] = vac[j];
    }
    __syncthreads();

    // ---- halo: idx 0..59 <- 60; 572..647 <- 571; zero 648..655 -----------
    if (tid < 36) {
        const int p = (tid < 15) ? tid * 4
                    : (tid < 34) ? 572 + (tid - 15) * 4
                                 : 648 + (tid - 34) * 4;
        const int u   = p >> 2;
        const int off = (u ^ ((u >> 3) & 7)) << 2;   // 16B-aligned
        const int soff = (tid < 15) ? swz_off(60) : swz_off(571);
        #pragma unroll
        for (int r8 = 0; r8 < TH; ++r8) {
            const float v = (tid < 34) ? sm[r8 * ROWF + soff] : 0.0f;
            *(float4*)&sm[r8 * ROWF + off] = make_float4(v, v, v, v);
        }
    }
    __syncthreads();

    // ---- horizontal: two 8-col spans per lane, two sequential row passes -
    const int r = tid >> 5;                          // 0..7
    const int L = tid & 31;                          // span A cols 8L.., B +256

    #pragma unroll 1
    for (int pass = 0; pass < 2; ++pass) {
        const float* __restrict__ bs = sm + (r + 8 * pass) * ROWF;

        float a0[8], a1[8], a2[8], a3[8];
        float b0[8], b1[8], b2[8], b3[8];
        float accA[8], accB[8];
        #pragma unroll
        for (int j = 0; j < 8; ++j) { accA[j] = 0.0f; accB[j] = 0.0f; }

        LOADG2(a0, b0, L)
        LOADG2(a1, b1, L + 1)
        LOADG2(a2, b2, L + 2)

        #pragma unroll 1
        for (int ko = 0; ko < 16; ko += 4) {
            H_OCT2(a0, a1, a2, a3, b0, b1, b2, b3, ko)
            H_OCT2(a1, a2, a3, a0, b1, b2, b3, b0, ko + 1)
            H_OCT2(a2, a3, a0, a1, b2, b3, b0, b1, ko + 2)
            H_OCT2(a3, a0, a1, a2, b3, b0, b1, b2, ko + 3)
        }

        float* __restrict__ dst = out + (size_t)plane * PLANE
                                      + (size_t)(r0 + r + 8 * pass) * WW
                                      + L * 8;
        *(float4*)(dst)       = make_float4(accA[0], accA[1], accA[2], accA[3]);
        *(float4*)(dst + 4)   = make_float4(accA[4], accA[5], accA[6], accA[7]);
        *(float4*)(dst + 256) = make_float4(accB[0], accB[1], accB[2], accB[3]);
        *(float4*)(dst + 260) = make_float4(accB[4], accB[5], accB[6], accB[7]);
    }
}

extern "C" void kernel_launch(void* const* d_in, const int* in_sizes, int n_in,
                              void* d_out, int out_size, void* d_ws, size_t ws_size,
                              hipStream_t stream) {
    const float* x     = (const float*)d_in[0];
    const float* sigma = (const float*)d_in[1];
    float* out = (float*)d_out;
    float* wg  = (float*)d_ws;                       // 512 B of workspace
    wk_prep<<<dim3(1), dim3(128), 0, stream>>>(sigma, wg);
    blur_fused<<<dim3(HH / TH, NIMG), dim3(256), 0, stream>>>(x, wg, out);
}

// Round 9
// 113.930 us; speedup vs baseline: 1.2525x; 1.2525x over previous
//
#include <hip/hip_runtime.h>

// Depthwise Gaussian blur K=121, replicate pad, separable, fp32. FUSED.
// R16 = R13 (53us best: 8-row tile, 6 blocks/CU resident, clean traffic)
// + V-phase 3-buffer LOAD-AHEAD-BY-2 pipeline: octet t computes from
// X_t,X_{t+1} (rows base..base+14, idx=ki+j<=14) while loading X_{t+2}.
// First use of a load is a full octet later (~512 cyc slack vs ~32 in
// R13) -> per-wave latency hiding, no reliance on TLP.
// R15 lesson: 16-row tile cut blocks/CU 6->3 (LDS 43K rounds to 50K) and
// halved TLP; its 16-row rotation also consumed loads in-octet (idx<=22
// overlaps the loaded buffer). dur 53->80.7. REVERTED. Occupancy capacity
// (blocks/CU x waves) is the latency-hiding resource; don't trade it away
// based on the derived average-occupancy counter.
// Kept from R13: scalar weights from d_ws (pre-normalized), two 8-col H
// spans, paired 32B-stride stores (only write-combine-clean pattern:
// R10/R11/R12 inflated WRITE 2.7-13x), XOR-swizzle LDS, XCD swizzle.

#define HH    512
#define WW    512
#define PLANE (512 * 512)
#define NIMG  24
#define ROWF  672                    // 168 16B-units/row, swizzle-bijective

// ---- pre-kernel: 128 normalized 1-D taps -> d_ws --------------------------
__global__ void wk_prep(const float* __restrict__ sigma,
                        float* __restrict__ wg) {
    const int tid = threadIdx.x;                     // 128 threads, 1 block
    const float s = sigma[0] * 8.0f + 16.0f;
    const float inv2v = 1.0f / (2.0f * s * s);
    float sum = 0.0f;
    #pragma unroll
    for (int k = 0; k <= 120; ++k) {
        const float c = (float)k - 60.0f;
        sum += __expf(-c * c * inv2v);
    }
    float g = 0.0f;
    if (tid < 121) {
        const float c = (float)tid - 60.0f;
        g = __expf(-c * c * inv2v);
    }
    wg[tid] = g / sum;               // taps 121..127 exactly 0
}

// dword offset within an LDS row for padded column `col` (swizzled)
__device__ __forceinline__ int swz_off(int col) {
    const int u = col >> 2;
    return ((u ^ ((u >> 3) & 7)) << 2) + (col & 3);
}

// Vertical octet, pipelined: A=X_t (rows base..), B=X_{t+1}; prefetch
// C=X_{t+2} (rows base+16.., clamped) issued BEFORE the FMAs.
// vac[j] += w[8KO+ki] * row[base+ki+j], idx=ki+j in [0,14] -> A/B only.
#define V_OCT_P(A, B, C, KO)                                              \
    { _Pragma("unroll")                                                   \
      for (int ki = 0; ki < 8; ++ki) {                                    \
          int rr = r0 - 44 + (KO) * 8 + ki;                               \
          rr = rr < 0 ? 0 : (rr > HH - 1 ? HH - 1 : rr);                  \
          C[ki] = *(const float2*)&src[(size_t)rr * WW];                  \
      }                                                                   \
      *(float4*)&wq[0] = *(const float4*)&wg[(KO) * 8];                   \
      *(float4*)&wq[4] = *(const float4*)&wg[(KO) * 8 + 4];               \
      _Pragma("unroll")                                                   \
      for (int ki = 0; ki < 8; ++ki) {                                    \
          const float wk = wq[ki];                                        \
          _Pragma("unroll")                                               \
          for (int j = 0; j < 8; ++j) {                                   \
              const int idx = ki + j;                                     \
              const float2 v = (idx < 8) ? A[idx] : B[idx - 8];           \
              vac[j].x += wk * v.x; vac[j].y += wk * v.y;                 \
          }                                                               \
      }                                                                   \
    }

// Final octet (KO=15): no prefetch; taps 121..127 are zero (B is X_16,
// loaded+clamped during octet 14, contributes only via zero taps).
#define V_OCT_NP(A, B, KO)                                                \
    { *(float4*)&wq[0] = *(const float4*)&wg[(KO) * 8];                   \
      *(float4*)&wq[4] = *(const float4*)&wg[(KO) * 8 + 4];               \
      _Pragma("unroll")                                                   \
      for (int ki = 0; ki < 8; ++ki) {                                    \
          const float wk = wq[ki];                                        \
          _Pragma("unroll")                                               \
          for (int j = 0; j < 8; ++j) {                                   \
              const int idx = ki + j;                                     \
              const float2 v = (idx < 8) ? A[idx] : B[idx - 8];           \
              vac[j].x += wk * v.x; vac[j].y += wk * v.y;                 \
          }                                                               \
      }                                                                   \
    }

// Load group G (span A) and G+32 (span B): one swizzled address serves all
// four b128s -- phys(2G+1)=phys(2G)^1, phys(u+64)=phys(u)+64 (+256 floats).
#define LOADG2(DA, DB, G)                                                 \
    { const int u_  = 2 * (G);                                            \
      const int o1_ = (u_ ^ ((u_ >> 3) & 7)) << 2;                        \
      const int o2_ = o1_ ^ 4;                                            \
      *(float4*)&DA[0] = *(const float4*)(bs + o1_);                      \
      *(float4*)&DA[4] = *(const float4*)(bs + o2_);                      \
      *(float4*)&DB[0] = *(const float4*)(bs + o1_ + 256);                \
      *(float4*)&DB[4] = *(const float4*)(bs + o2_ + 256); }

// One octet, TWO 8-col spans (A: groups L+.., B: groups L+32+..)
#define H_OCT2(A0, A1, A2, A3, B0, B1, B2, B3, KO)                        \
    { LOADG2(A3, B3, L + (KO) + 3)                                        \
      *(float4*)&wq[0] = *(const float4*)&wg[(KO) * 8];                   \
      *(float4*)&wq[4] = *(const float4*)&wg[(KO) * 8 + 4];               \
      _Pragma("unroll")                                                   \
      for (int ki = 0; ki < 8; ++ki) {                                    \
          const float wk = wq[ki];                                        \
          _Pragma("unroll")                                               \
          for (int j = 0; j < 8; ++j) {                                   \
              const int idx = ki + j;                                     \
              const float vA = (idx < 8) ? A0[idx]                        \
                             : (idx < 16) ? A1[idx - 8] : A2[idx - 16];   \
              const float vB = (idx < 8) ? B0[idx]                        \
                             : (idx < 16) ? B1[idx - 8] : B2[idx - 16];   \
              accA[j] += wk * vA;                                         \
              accB[j] += wk * vB;                                         \
          }                                                               \
      }                                                                   \
    }

__global__ __launch_bounds__(256, 6) void blur_fused(
        const float* __restrict__ x, const float* __restrict__ wg,
        float* __restrict__ out) {
    __shared__ float sm[8 * ROWF];                   // 21504 B
    const int tid = threadIdx.x;

    // XCD swizzle: linear id -> contiguous 192-tile span per XCD (%8 rr).
    const int lid   = blockIdx.x + gridDim.x * blockIdx.y;   // 0..1535
    const int tile  = (lid & 7) * 192 + (lid >> 3);
    const int r0    = (tile & 63) * 8;               // output rows r0..r0+7
    const int plane = tile >> 6;

    const int c0 = tid * 2;                          // this thread's 2 cols
    const float* __restrict__ src = x + (size_t)plane * PLANE + c0;

    // ---- vertical: 8 rows x 2 cols, 3-buffer load-ahead-by-2 pipeline ----
    float2 w0[8], w1[8], w2[8], vac[8];
    float  wq[8];
    #pragma unroll
    for (int m = 0; m < 8; ++m) {                    // X_0: rows r0-60..r0-53
        int rr = r0 - 60 + m;
        rr = rr < 0 ? 0 : rr;
        w0[m] = *(const float2*)&src[(size_t)rr * WW];
    }
    #pragma unroll
    for (int m = 0; m < 8; ++m) {                    // X_1: rows r0-52..r0-45
        int rr = r0 - 52 + m;
        rr = rr < 0 ? 0 : rr;
        w1[m] = *(const float2*)&src[(size_t)rr * WW];
    }
    #pragma unroll
    for (int j = 0; j < 8; ++j) vac[j] = make_float2(0.f, 0.f);

    #pragma unroll 1
    for (int ko = 0; ko < 15; ko += 3) {             // octets 0..14, period-3
        V_OCT_P(w0, w1, w2, ko)
        V_OCT_P(w1, w2, w0, ko + 1)
        V_OCT_P(w2, w0, w1, ko + 2)
    }
    V_OCT_NP(w0, w1, 15)                             // octet 15, no prefetch

    // write intermediate at halo offset +60 (swizzled; float2 stays in-unit)
    {
        const int off = swz_off(c0 + 60);            // col even -> within-unit
        #pragma unroll
        for (int j = 0; j < 8; ++j)
            *(float2*)&sm[j * ROWF + off] = vac[j];
    }
    __syncthreads();

    // ---- halo: idx 0..59 <- 60; 572..647 <- 571; zero 648..655 -----------
    if (tid < 36) {
        const int p = (tid < 15) ? tid * 4
                    : (tid < 34) ? 572 + (tid - 15) * 4
                                 : 648 + (tid - 34) * 4;
        const int u   = p >> 2;
        const int off = (u ^ ((u >> 3) & 7)) << 2;   // 16B-aligned
        const int soff = (tid < 15) ? swz_off(60) : swz_off(571);
        #pragma unroll
        for (int r8 = 0; r8 < 8; ++r8) {
            const float v = (tid < 34) ? sm[r8 * ROWF + soff] : 0.0f;
            *(float4*)&sm[r8 * ROWF + off] = make_float4(v, v, v, v);
        }
    }
    __syncthreads();

    // ---- horizontal: two 8-col spans per lane, rotating 4-octet windows --
    const int r = tid >> 5;                          // 0..7
    const int L = tid & 31;                          // span A cols 8L.., B +256
    const float* __restrict__ bs = sm + r * ROWF;

    float a0[8], a1[8], a2[8], a3[8];
    float b0[8], b1[8], b2[8], b3[8];
    float accA[8], accB[8];
    #pragma unroll
    for (int j = 0; j < 8; ++j) { accA[j] = 0.0f; accB[j] = 0.0f; }

    LOADG2(a0, b0, L)
    LOADG2(a1, b1, L + 1)
    LOADG2(a2, b2, L + 2)

    #pragma unroll 1
    for (int ko = 0; ko < 16; ko += 4) {
        H_OCT2(a0, a1, a2, a3, b0, b1, b2, b3, ko)
        H_OCT2(a1, a2, a3, a0, b1, b2, b3, b0, ko + 1)
        H_OCT2(a2, a3, a0, a1, b2, b3, b0, b1, ko + 2)
        H_OCT2(a3, a0, a1, a2, b3, b0, b1, b2, ko + 3)
    }

    float* __restrict__ dst = out + (size_t)plane * PLANE
                                  + (size_t)(r0 + r) * WW + L * 8;
    *(float4*)(dst)       = make_float4(accA[0], accA[1], accA[2], accA[3]);
    *(float4*)(dst + 4)   = make_float4(accA[4], accA[5], accA[6], accA[7]);
    *(float4*)(dst + 256) = make_float4(accB[0], accB[1], accB[2], accB[3]);
    *(float4*)(dst + 260) = make_float4(accB[4], accB[5], accB[6], accB[7]);
}

extern "C" void kernel_launch(void* const* d_in, const int* in_sizes, int n_in,
                              void* d_out, int out_size, void* d_ws, size_t ws_size,
                              hipStream_t stream) {
    const float* x     = (const float*)d_in[0];
    const float* sigma = (const float*)d_in[1];
    float* out = (float*)d_out;
    float* wg  = (float*)d_ws;                       // 512 B of workspace
    wk_prep<<<dim3(1), dim3(128), 0, stream>>>(sigma, wg);
    blur_fused<<<dim3(HH / 8, NIMG), dim3(256), 0, stream>>>(x, wg, out);
}